// Round 3
// baseline (4686.578 us; speedup 1.0000x reference)
//
#include <hip/hip_runtime.h>

typedef unsigned short u16;
typedef unsigned int   u32;
typedef __attribute__((ext_vector_type(8))) short s8v;   // 8 x bf16 bits (4 VGPRs)
typedef __attribute__((ext_vector_type(4))) float f4v;   // MFMA accumulator

#define B_SZ  64
#define T_LEN 512
#define U_DIM 256
#define E_DIM 300
#define EP    320          // E padded to multiple of 32
#define G3    768          // 3*U
#define NTOT  1536         // both directions concatenated
#define C_DIM 20
#define BT    (B_SZ*T_LEN)

__device__ __forceinline__ float bf2f(u16 h){ return __uint_as_float(((u32)h)<<16); }
__device__ __forceinline__ u16 f2bf(float f){
  u32 u = __float_as_uint(f);
  u32 r = (u + 0x7FFFu + ((u>>16)&1u)) >> 16;   // RNE
  return (u16)r;
}

// ------------- embedding gather f32 -> bf16, K-pad (300 -> 320, zeros) --------
__global__ void embed_pad(const int* __restrict__ x, const float* __restrict__ emb,
                          u16* __restrict__ e){
  int idx = blockIdx.x*256 + threadIdx.x;
  if(idx >= BT*EP) return;
  int row = idx / EP, col = idx - row*EP;
  u16 v = 0;
  if(col < E_DIM) v = f2bf(emb[(size_t)x[row]*E_DIM + col]);
  e[idx] = v;
}

// ------ transpose + concat two f32 [K,768] sources -> bf16 dst[N][Kp] ---------
__global__ void transpose_cc(const float* __restrict__ A, const float* __restrict__ Bm,
                             u16* __restrict__ dst, int K, int Kp, int N){
  int idx = blockIdx.x*256 + threadIdx.x;
  if(idx >= N*Kp) return;
  int n = idx / Kp, k = idx - n*Kp;
  u16 v = 0;
  if(k < K){
    const float* s = (n < G3) ? A : Bm;
    int nn = (n < G3) ? n : n - G3;
    v = f2bf(s[(size_t)k*G3 + nn]);
  }
  dst[idx] = v;
}

// ---------------- GEMM: C[M,1536] = A[M,Kp] @ BT^T + bias (bf16 out) ----------
// BT_ is [1536][Kp] (pre-transposed weights, bf16). 128x128 tile, 4 waves.
__global__ __launch_bounds__(256) void gemm_bt(
    const u16* __restrict__ A, const u16* __restrict__ BT_, u16* __restrict__ C,
    int Kp, const float* __restrict__ biasA, const float* __restrict__ biasB)
{
  __shared__ u16 Al[128][40];   // +8 pad breaks bank collisions
  __shared__ u16 Bl[128][40];
  int tid = threadIdx.x;
  int w = tid>>6, l = tid&63, lc = l&15, quad = l>>4;
  int wm = w>>1, wn = w&1;
  int mb = blockIdx.y*128, nb = blockIdx.x*128;

  f4v acc[4][4];
  #pragma unroll
  for(int i=0;i<4;i++)
    #pragma unroll
    for(int j=0;j<4;j++) acc[i][j] = (f4v){0.f,0.f,0.f,0.f};

  int nk = Kp >> 5;
  for(int kt=0; kt<nk; kt++){
    __syncthreads();
    {
      int c0 = tid, c1 = tid + 256;
      int r0 = c0>>2, k80 = c0&3;
      int r1 = c1>>2, k81 = c1&3;
      *(s8v*)&Al[r0][k80*8] = *(const s8v*)(A   + (size_t)(mb+r0)*Kp + kt*32 + k80*8);
      *(s8v*)&Al[r1][k81*8] = *(const s8v*)(A   + (size_t)(mb+r1)*Kp + kt*32 + k81*8);
      *(s8v*)&Bl[r0][k80*8] = *(const s8v*)(BT_ + (size_t)(nb+r0)*Kp + kt*32 + k80*8);
      *(s8v*)&Bl[r1][k81*8] = *(const s8v*)(BT_ + (size_t)(nb+r1)*Kp + kt*32 + k81*8);
    }
    __syncthreads();
    s8v af[4], bf[4];
    #pragma unroll
    for(int i=0;i<4;i++) af[i] = *(const s8v*)&Al[wm*64 + i*16 + lc][quad*8];
    #pragma unroll
    for(int j=0;j<4;j++) bf[j] = *(const s8v*)&Bl[wn*64 + j*16 + lc][quad*8];
    #pragma unroll
    for(int i=0;i<4;i++)
      #pragma unroll
      for(int j=0;j<4;j++)
        acc[i][j] = __builtin_amdgcn_mfma_f32_16x16x32_bf16(af[i], bf[j], acc[i][j],0,0,0);
  }
  #pragma unroll
  for(int j=0;j<4;j++){
    int col = nb + wn*64 + j*16 + lc;
    float bias = (col < G3) ? biasA[col] : biasB[col - G3];
    #pragma unroll
    for(int i=0;i<4;i++){
      int row0 = mb + wm*64 + i*16 + quad*4;
      #pragma unroll
      for(int r=0;r<4;r++)
        C[(size_t)(row0+r)*NTOT + col] = f2bf(acc[i][j][r] + bias);
    }
  }
}

// ---------------- GRU scan, one layer both directions -------------------------
// grid = 8 blocks: dir = blockIdx&1, batch-group = blockIdx>>1 (16 batches each).
// 512 threads = 8 waves; wave w owns u in [32w, 32w+32): gate cols {g*256+32w..+32}
// so gate math for a given u stays in-register. rk resident in VGPRs:
// brk = 3 gates x 2 subtiles x 8 ktiles = 48 s8v = 192 VGPRs/wave -> 2 waves/SIMD.
__global__ __launch_bounds__(512,1) void gru_scan(
    const u16* __restrict__ xw,    // [BT,1536] bf16 (= X@K + b0, both dirs)
    const u16* __restrict__ rkT,   // [2][768][256] bf16 transposed recurrent kernels
    const float* __restrict__ bF, const float* __restrict__ bB,  // b[2][768] f32
    u16* __restrict__ h1out,       // mode0: [BT,512]
    float* __restrict__ h2out,     // mode1: [64,512] final states
    int mode)
{
  int dir = blockIdx.x & 1, grp = blockIdx.x >> 1;
  int b0 = grp*16;
  int tid = threadIdx.x;
  int w = tid>>6, l = tid&63, lc = l&15, quad = l>>4;

  __shared__ u16 hb[2][16][264];   // double-buffered h (bf16), +8 pad
  for(int i=tid; i<2*16*264; i+=512) ((u16*)hb)[i] = 0;

  const u16*   rkd  = rkT + (size_t)dir*G3*U_DIM;
  const float* bias = (dir ? bB : bF) + G3;   // row 1 = recurrent bias

  // resident B-fragments: brk[gate][sub][ktile]
  s8v brk[3][2][8];
  #pragma unroll
  for(int g=0; g<3; g++)
    #pragma unroll
    for(int s=0; s<2; s++){
      int n = g*256 + w*32 + s*16 + lc;
      #pragma unroll
      for(int kt=0; kt<8; kt++)
        brk[g][s][kt] = *(const s8v*)(rkd + (size_t)n*U_DIM + kt*32 + quad*8);
    }
  float bg[3][2];
  #pragma unroll
  for(int g=0;g<3;g++)
    #pragma unroll
    for(int s=0;s<2;s++)
      bg[g][s] = bias[g*256 + w*32 + s*16 + lc];

  __syncthreads();

  int cur = 0;
  for(int step=0; step<T_LEN; step++){
    int t = dir ? (T_LEN-1-step) : step;

    // xw loads for this step (issued before MFMA so latency overlaps)
    u16 xu[3][2][4];
    #pragma unroll
    for(int g=0;g<3;g++)
      #pragma unroll
      for(int s=0;s<2;s++)
        #pragma unroll
        for(int r=0;r<4;r++){
          int m = quad*4 + r;
          xu[g][s][r] = xw[((size_t)(b0+m)*T_LEN + t)*NTOT + dir*G3 + g*256 + w*32 + s*16 + lc];
        }

    f4v acc[3][2];
    #pragma unroll
    for(int g=0;g<3;g++)
      #pragma unroll
      for(int s=0;s<2;s++) acc[g][s] = (f4v){0.f,0.f,0.f,0.f};

    #pragma unroll
    for(int kt=0; kt<8; kt++){
      s8v a = *(const s8v*)&hb[cur][lc][kt*32 + quad*8];
      #pragma unroll
      for(int g=0;g<3;g++)
        #pragma unroll
        for(int s=0;s<2;s++)
          acc[g][s] = __builtin_amdgcn_mfma_f32_16x16x32_bf16(a, brk[g][s][kt], acc[g][s],0,0,0);
    }

    #pragma unroll
    for(int s=0;s<2;s++){
      int u = w*32 + s*16 + lc;
      #pragma unroll
      for(int r=0;r<4;r++){
        int m = quad*4 + r;
        float zf = acc[0][s][r] + bg[0][s] + bf2f(xu[0][s][r]);
        float rf = acc[1][s][r] + bg[1][s] + bf2f(xu[1][s][r]);
        float rh = acc[2][s][r] + bg[2][s];
        float xh = bf2f(xu[2][s][r]);
        zf = 1.f / (1.f + __expf(-zf));
        rf = 1.f / (1.f + __expf(-rf));
        float hc = xh + rf*rh;
        hc = fminf(fmaxf(hc, -15.f), 15.f);
        float e2 = __expf(2.f*hc);
        float th = (e2 - 1.f) / (e2 + 1.f);
        float hp = bf2f(hb[cur][m][u]);
        float hn = zf*hp + (1.f - zf)*th;
        u16 hbf = f2bf(hn);
        hb[cur^1][m][u] = hbf;
        if(mode == 0)
          h1out[((size_t)(b0+m)*T_LEN + t)*(2*U_DIM) + dir*U_DIM + u] = hbf;
        else if(step == T_LEN-1)
          h2out[(size_t)(b0+m)*(2*U_DIM) + dir*U_DIM + u] = hn;
      }
    }
    __syncthreads();
    cur ^= 1;
  }
}

// ---------------- final projection + softmax (f32 output!) --------------------
__global__ void out_softmax(const float* __restrict__ h2, const float* __restrict__ wout,
                            const float* __restrict__ bout, float* __restrict__ out)
{
  __shared__ float lg[C_DIM];
  int b = blockIdx.x, l = threadIdx.x;   // 64 threads = 1 wave
  float acc[C_DIM];
  #pragma unroll
  for(int c=0;c<C_DIM;c++) acc[c] = 0.f;
  for(int k=l; k<2*U_DIM; k+=64){
    float hv = h2[b*2*U_DIM + k];
    #pragma unroll
    for(int c=0;c<C_DIM;c++) acc[c] += hv * wout[k*C_DIM + c];
  }
  #pragma unroll
  for(int c=0;c<C_DIM;c++){
    float v = acc[c];
    for(int off=32; off; off>>=1) v += __shfl_down(v, off);
    if(l==0) lg[c] = v + bout[c];
  }
  __syncthreads();
  if(l==0){
    float mx = lg[0];
    for(int c=1;c<C_DIM;c++) mx = fmaxf(mx, lg[c]);
    float sum = 0.f, ex[C_DIM];
    for(int c=0;c<C_DIM;c++){ ex[c] = __expf(lg[c]-mx); sum += ex[c]; }
    for(int c=0;c<C_DIM;c++) out[b*C_DIM + c] = ex[c]/sum;
  }
}

extern "C" void kernel_launch(void* const* d_in, const int* in_sizes, int n_in,
                              void* d_out, int out_size, void* d_ws, size_t ws_size,
                              hipStream_t stream)
{
  const int*   x    = (const int*)d_in[0];
  const float* emb  = (const float*)d_in[1];
  const float* k1f  = (const float*)d_in[2];
  const float* rk1f = (const float*)d_in[3];
  const float* b1f  = (const float*)d_in[4];
  const float* k1b  = (const float*)d_in[5];
  const float* rk1b = (const float*)d_in[6];
  const float* b1b  = (const float*)d_in[7];
  const float* k2f  = (const float*)d_in[8];
  const float* rk2f = (const float*)d_in[9];
  const float* b2f  = (const float*)d_in[10];
  const float* k2b  = (const float*)d_in[11];
  const float* rk2b = (const float*)d_in[12];
  const float* b2b  = (const float*)d_in[13];
  const float* wout = (const float*)d_in[14];
  const float* bout = (const float*)d_in[15];

  // workspace layout: small buffers first, then h1/e_pad (aliased), then xwb
  char* ws = (char*)d_ws;
  u16*  k1t   = (u16*)(ws);                       // 983,040 B     [1536,320]
  u16*  k2t   = (u16*)(ws + 983040);              // 1,572,864 B   [1536,512]
  u16*  rkt   = (u16*)(ws + 2555904);             // 1,572,864 B   4x[768,256]
  float* h2   = (float*)(ws + 4128768);           // 131,072 B     [64,512]
  u16*  h1    = (u16*)(ws + 4259840);             // 33,554,432 B  [BT,512]
  u16*  e_pad = (u16*)(ws + 4259840);             // 20,971,520 B  [BT,320] (alias h1)
  u16*  xwb   = (u16*)(ws + 37814272);            // 100,663,296 B [BT,1536]  (end ~138.5 MB)

  transpose_cc<<<(NTOT*EP +255)/256,256,0,stream>>>(k1f, k1b, k1t, E_DIM, EP, NTOT);
  transpose_cc<<<(NTOT*512+255)/256,256,0,stream>>>(k2f, k2b, k2t, 512, 512, NTOT);
  transpose_cc<<<(G3*U_DIM+255)/256,256,0,stream>>>(rk1f, rk1f, rkt,                U_DIM, U_DIM, G3);
  transpose_cc<<<(G3*U_DIM+255)/256,256,0,stream>>>(rk1b, rk1b, rkt + 1*G3*U_DIM,   U_DIM, U_DIM, G3);
  transpose_cc<<<(G3*U_DIM+255)/256,256,0,stream>>>(rk2f, rk2f, rkt + 2*G3*U_DIM,   U_DIM, U_DIM, G3);
  transpose_cc<<<(G3*U_DIM+255)/256,256,0,stream>>>(rk2b, rk2b, rkt + 3*G3*U_DIM,   U_DIM, U_DIM, G3);

  embed_pad<<<(BT*EP)/256,256,0,stream>>>(x, emb, e_pad);

  // layer 1: xw = e @ K1 + b0 ; scan -> h1
  gemm_bt<<<dim3(12,256),256,0,stream>>>(e_pad, k1t, xwb, EP, b1f, b1b);
  gru_scan<<<8,512,0,stream>>>(xwb, rkt, b1f, b1b, h1, nullptr, 0);

  // layer 2: xw = h1 @ K2 + b0 ; scan -> h2 (final states only)
  gemm_bt<<<dim3(12,256),256,0,stream>>>(h1, k2t, xwb, 512, b2f, b2b);
  gru_scan<<<8,512,0,stream>>>(xwb, rkt + 2*G3*U_DIM, b2f, b2b, nullptr, h2, 1);

  out_softmax<<<64,64,0,stream>>>(h2, wout, bout, (float*)d_out);
}

// Round 4
// 4168.505 us; speedup vs baseline: 1.1243x; 1.1243x over previous
//
#include <hip/hip_runtime.h>

typedef unsigned short u16;
typedef unsigned int   u32;
typedef __attribute__((ext_vector_type(8))) short s8v;   // 8 x bf16 bits (4 VGPRs)
typedef __attribute__((ext_vector_type(4))) float f4v;   // MFMA accumulator

#define B_SZ  64
#define T_LEN 512
#define U_DIM 256
#define E_DIM 300
#define EP    320          // E padded to multiple of 32
#define G3    768          // 3*U
#define NTOT  1536         // both directions concatenated
#define C_DIM 20
#define BT    (B_SZ*T_LEN)

__device__ __forceinline__ float bf2f(u16 h){ return __uint_as_float(((u32)h)<<16); }
__device__ __forceinline__ u16 f2bf(float f){
  u32 u = __float_as_uint(f);
  u32 r = (u + 0x7FFFu + ((u>>16)&1u)) >> 16;   // RNE
  return (u16)r;
}

// ------------- embedding gather f32 -> bf16, K-pad (300 -> 320, zeros) --------
__global__ void embed_pad(const int* __restrict__ x, const float* __restrict__ emb,
                          u16* __restrict__ e){
  int idx = blockIdx.x*256 + threadIdx.x;
  if(idx >= BT*EP) return;
  int row = idx / EP, col = idx - row*EP;
  u16 v = 0;
  if(col < E_DIM) v = f2bf(emb[(size_t)x[row]*E_DIM + col]);
  e[idx] = v;
}

// ------ transpose + concat two f32 [K,768] sources -> bf16 dst[N][Kp] ---------
__global__ void transpose_cc(const float* __restrict__ A, const float* __restrict__ Bm,
                             u16* __restrict__ dst, int K, int Kp, int N){
  int idx = blockIdx.x*256 + threadIdx.x;
  if(idx >= N*Kp) return;
  int n = idx / Kp, k = idx - n*Kp;
  u16 v = 0;
  if(k < K){
    const float* s = (n < G3) ? A : Bm;
    int nn = (n < G3) ? n : n - G3;
    v = f2bf(s[(size_t)k*G3 + nn]);
  }
  dst[idx] = v;
}

// ---------------- GEMM: C[M,1536] = A[M,Kp] @ BT^T + bias (bf16 out) ----------
__global__ __launch_bounds__(256) void gemm_bt(
    const u16* __restrict__ A, const u16* __restrict__ BT_, u16* __restrict__ C,
    int Kp, const float* __restrict__ biasA, const float* __restrict__ biasB)
{
  __shared__ u16 Al[128][40];   // +8 pad breaks bank collisions
  __shared__ u16 Bl[128][40];
  int tid = threadIdx.x;
  int w = tid>>6, l = tid&63, lc = l&15, quad = l>>4;
  int wm = w>>1, wn = w&1;
  int mb = blockIdx.y*128, nb = blockIdx.x*128;

  f4v acc[4][4];
  #pragma unroll
  for(int i=0;i<4;i++)
    #pragma unroll
    for(int j=0;j<4;j++) acc[i][j] = (f4v){0.f,0.f,0.f,0.f};

  int nk = Kp >> 5;
  for(int kt=0; kt<nk; kt++){
    __syncthreads();
    {
      int c0 = tid, c1 = tid + 256;
      int r0 = c0>>2, k80 = c0&3;
      int r1 = c1>>2, k81 = c1&3;
      *(s8v*)&Al[r0][k80*8] = *(const s8v*)(A   + (size_t)(mb+r0)*Kp + kt*32 + k80*8);
      *(s8v*)&Al[r1][k81*8] = *(const s8v*)(A   + (size_t)(mb+r1)*Kp + kt*32 + k81*8);
      *(s8v*)&Bl[r0][k80*8] = *(const s8v*)(BT_ + (size_t)(nb+r0)*Kp + kt*32 + k80*8);
      *(s8v*)&Bl[r1][k81*8] = *(const s8v*)(BT_ + (size_t)(nb+r1)*Kp + kt*32 + k81*8);
    }
    __syncthreads();
    s8v af[4], bf[4];
    #pragma unroll
    for(int i=0;i<4;i++) af[i] = *(const s8v*)&Al[wm*64 + i*16 + lc][quad*8];
    #pragma unroll
    for(int j=0;j<4;j++) bf[j] = *(const s8v*)&Bl[wn*64 + j*16 + lc][quad*8];
    #pragma unroll
    for(int i=0;i<4;i++)
      #pragma unroll
      for(int j=0;j<4;j++)
        acc[i][j] = __builtin_amdgcn_mfma_f32_16x16x32_bf16(af[i], bf[j], acc[i][j],0,0,0);
  }
  #pragma unroll
  for(int j=0;j<4;j++){
    int col = nb + wn*64 + j*16 + lc;
    float bias = (col < G3) ? biasA[col] : biasB[col - G3];
    #pragma unroll
    for(int i=0;i<4;i++){
      int row0 = mb + wm*64 + i*16 + quad*4;
      #pragma unroll
      for(int r=0;r<4;r++)
        C[(size_t)(row0+r)*NTOT + col] = f2bf(acc[i][j][r] + bias);
    }
  }
}

// ---------------- GRU scan, one layer both directions -------------------------
// grid = 8 blocks: dir = blockIdx&1, batch-group = blockIdx>>1 (16 batches each).
// 512 threads = 8 waves; wave w owns u in [32w, 32w+32): gate cols {g*256+32w..+32}.
// rk resident in VGPRs: brk = 3x2x8 s8v = 192 VGPRs/wave.
// __launch_bounds__(512,2): 2 waves/SIMD -> 256-VGPR budget (fits brk+acc+xu).
template<int MODE>
__global__ __launch_bounds__(512,2) void gru_scan(
    const u16* __restrict__ xw,    // [BT,1536] bf16 (= X@K + b0, both dirs)
    const u16* __restrict__ rkT,   // [2][768][256] bf16 transposed recurrent kernels
    const float* __restrict__ bF, const float* __restrict__ bB,  // b[2][768] f32
    u16* __restrict__ h1out,       // MODE 0: [BT,512]
    float* __restrict__ h2out)     // MODE 1: [64,512] final states
{
  int dir = blockIdx.x & 1, grp = blockIdx.x >> 1;
  int b0 = grp*16;
  int tid = threadIdx.x;
  int w = tid>>6, l = tid&63, lc = l&15, quad = l>>4;

  __shared__ u16 hb[2][16][264];   // double-buffered h (bf16), +8 pad
  for(int i=tid; i<2*16*264; i+=512) ((u16*)hb)[i] = 0;

  const u16*   rkd  = rkT + (size_t)dir*G3*U_DIM;
  const float* bias = (dir ? bB : bF) + G3;   // row 1 = recurrent bias

  // resident B-fragments: brk[gate][sub][ktile]  (192 VGPRs)
  s8v brk[3][2][8];
  #pragma unroll
  for(int g=0; g<3; g++)
    #pragma unroll
    for(int s=0; s<2; s++){
      int n = g*256 + w*32 + s*16 + lc;
      #pragma unroll
      for(int kt=0; kt<8; kt++)
        brk[g][s][kt] = *(const s8v*)(rkd + (size_t)n*U_DIM + kt*32 + quad*8);
    }
  float bg[3][2];
  #pragma unroll
  for(int g=0;g<3;g++)
    #pragma unroll
    for(int s=0;s<2;s++)
      bg[g][s] = bias[g*256 + w*32 + s*16 + lc];

  int t0 = dir ? (T_LEN-1) : 0;
  long tstride  = dir ? -(long)NTOT      : (long)NTOT;       // xw elems/step
  long hstride  = dir ? -(long)(2*U_DIM) : (long)(2*U_DIM);  // h1out elems/step

  // per-row base pointers (imm offsets cover g*512B + s*32B <= 1056B)
  const u16* xwp[4];
  u16* hop[4];
  #pragma unroll
  for(int r=0;r<4;r++){
    int m = quad*4 + r;
    xwp[r] = xw + ((size_t)(b0+m)*T_LEN + t0)*NTOT + dir*G3 + w*32 + lc;
    hop[r] = (MODE==0) ? (h1out + ((size_t)(b0+m)*T_LEN + t0)*(2*U_DIM) + dir*U_DIM + w*32 + lc)
                       : nullptr;
  }

  __syncthreads();

  int cur = 0;
  for(int step=0; step<T_LEN; step++){
    // xw loads for this step (independent of h -> issue before MFMA)
    u16 xu[3][2][4];
    #pragma unroll
    for(int r=0;r<4;r++)
      #pragma unroll
      for(int g=0;g<3;g++)
        #pragma unroll
        for(int s=0;s<2;s++)
          xu[g][s][r] = xwp[r][g*256 + s*16];

    f4v acc[3][2];
    #pragma unroll
    for(int g=0;g<3;g++)
      #pragma unroll
      for(int s=0;s<2;s++) acc[g][s] = (f4v){0.f,0.f,0.f,0.f};

    #pragma unroll
    for(int kt=0; kt<8; kt++){
      s8v a = *(const s8v*)&hb[cur][lc][kt*32 + quad*8];
      #pragma unroll
      for(int g=0;g<3;g++)
        #pragma unroll
        for(int s=0;s<2;s++)
          acc[g][s] = __builtin_amdgcn_mfma_f32_16x16x32_bf16(a, brk[g][s][kt], acc[g][s],0,0,0);
    }

    #pragma unroll
    for(int s=0;s<2;s++){
      int u = w*32 + s*16 + lc;
      #pragma unroll
      for(int r=0;r<4;r++){
        int m = quad*4 + r;
        float zf = acc[0][s][r] + bg[0][s] + bf2f(xu[0][s][r]);
        float rf = acc[1][s][r] + bg[1][s] + bf2f(xu[1][s][r]);
        float rh = acc[2][s][r] + bg[2][s];
        float xh = bf2f(xu[2][s][r]);
        zf = 1.f / (1.f + __expf(-zf));
        rf = 1.f / (1.f + __expf(-rf));
        float hc = xh + rf*rh;
        hc = fminf(fmaxf(hc, -15.f), 15.f);
        float e2 = __expf(2.f*hc);
        float th = (e2 - 1.f) / (e2 + 1.f);
        float hp = bf2f(hb[cur][m][u]);
        float hn = zf*hp + (1.f - zf)*th;
        u16 hbf = f2bf(hn);
        hb[cur^1][m][u] = hbf;
        if(MODE == 0)
          hop[r][s*16] = hbf;
        else if(step == T_LEN-1)
          h2out[(size_t)(b0+m)*(2*U_DIM) + dir*U_DIM + u] = hn;
      }
    }

    #pragma unroll
    for(int r=0;r<4;r++){
      xwp[r] += tstride;
      if(MODE==0) hop[r] += hstride;
    }
    __syncthreads();
    cur ^= 1;
  }
}

// ---------------- final projection + softmax (f32 output) ---------------------
__global__ void out_softmax(const float* __restrict__ h2, const float* __restrict__ wout,
                            const float* __restrict__ bout, float* __restrict__ out)
{
  __shared__ float lg[C_DIM];
  int b = blockIdx.x, l = threadIdx.x;   // 64 threads = 1 wave
  float acc[C_DIM];
  #pragma unroll
  for(int c=0;c<C_DIM;c++) acc[c] = 0.f;
  for(int k=l; k<2*U_DIM; k+=64){
    float hv = h2[b*2*U_DIM + k];
    #pragma unroll
    for(int c=0;c<C_DIM;c++) acc[c] += hv * wout[k*C_DIM + c];
  }
  #pragma unroll
  for(int c=0;c<C_DIM;c++){
    float v = acc[c];
    for(int off=32; off; off>>=1) v += __shfl_down(v, off);
    if(l==0) lg[c] = v + bout[c];
  }
  __syncthreads();
  if(l==0){
    float mx = lg[0];
    for(int c=1;c<C_DIM;c++) mx = fmaxf(mx, lg[c]);
    float sum = 0.f, ex[C_DIM];
    for(int c=0;c<C_DIM;c++){ ex[c] = __expf(lg[c]-mx); sum += ex[c]; }
    for(int c=0;c<C_DIM;c++) out[b*C_DIM + c] = ex[c]/sum;
  }
}

extern "C" void kernel_launch(void* const* d_in, const int* in_sizes, int n_in,
                              void* d_out, int out_size, void* d_ws, size_t ws_size,
                              hipStream_t stream)
{
  const int*   x    = (const int*)d_in[0];
  const float* emb  = (const float*)d_in[1];
  const float* k1f  = (const float*)d_in[2];
  const float* rk1f = (const float*)d_in[3];
  const float* b1f  = (const float*)d_in[4];
  const float* k1b  = (const float*)d_in[5];
  const float* rk1b = (const float*)d_in[6];
  const float* b1b  = (const float*)d_in[7];
  const float* k2f  = (const float*)d_in[8];
  const float* rk2f = (const float*)d_in[9];
  const float* b2f  = (const float*)d_in[10];
  const float* k2b  = (const float*)d_in[11];
  const float* rk2b = (const float*)d_in[12];
  const float* b2b  = (const float*)d_in[13];
  const float* wout = (const float*)d_in[14];
  const float* bout = (const float*)d_in[15];

  // workspace layout: small buffers first, then h1/e_pad (aliased), then xwb
  char* ws = (char*)d_ws;
  u16*  k1t   = (u16*)(ws);                       // 983,040 B     [1536,320]
  u16*  k2t   = (u16*)(ws + 983040);              // 1,572,864 B   [1536,512]
  u16*  rkt   = (u16*)(ws + 2555904);             // 1,572,864 B   4x[768,256]
  float* h2   = (float*)(ws + 4128768);           // 131,072 B     [64,512]
  u16*  h1    = (u16*)(ws + 4259840);             // 33,554,432 B  [BT,512]
  u16*  e_pad = (u16*)(ws + 4259840);             // 20,971,520 B  [BT,320] (alias h1)
  u16*  xwb   = (u16*)(ws + 37814272);            // 100,663,296 B [BT,1536]

  transpose_cc<<<(NTOT*EP +255)/256,256,0,stream>>>(k1f, k1b, k1t, E_DIM, EP, NTOT);
  transpose_cc<<<(NTOT*512+255)/256,256,0,stream>>>(k2f, k2b, k2t, 512, 512, NTOT);
  transpose_cc<<<(G3*U_DIM+255)/256,256,0,stream>>>(rk1f, rk1f, rkt,                U_DIM, U_DIM, G3);
  transpose_cc<<<(G3*U_DIM+255)/256,256,0,stream>>>(rk1b, rk1b, rkt + 1*G3*U_DIM,   U_DIM, U_DIM, G3);
  transpose_cc<<<(G3*U_DIM+255)/256,256,0,stream>>>(rk2f, rk2f, rkt + 2*G3*U_DIM,   U_DIM, U_DIM, G3);
  transpose_cc<<<(G3*U_DIM+255)/256,256,0,stream>>>(rk2b, rk2b, rkt + 3*G3*U_DIM,   U_DIM, U_DIM, G3);

  embed_pad<<<(BT*EP)/256,256,0,stream>>>(x, emb, e_pad);

  // layer 1: xw = e @ K1 + b0 ; scan -> h1
  gemm_bt<<<dim3(12,256),256,0,stream>>>(e_pad, k1t, xwb, EP, b1f, b1b);
  gru_scan<0><<<8,512,0,stream>>>(xwb, rkt, b1f, b1b, h1, nullptr);

  // layer 2: xw = h1 @ K2 + b0 ; scan -> h2 (final states only)
  gemm_bt<<<dim3(12,256),256,0,stream>>>(h1, k2t, xwb, 512, b2f, b2b);
  gru_scan<1><<<8,512,0,stream>>>(xwb, rkt + 2*G3*U_DIM, b2f, b2b, nullptr, h2);

  out_softmax<<<64,64,0,stream>>>(h2, wout, bout, (float*)d_out);
}

// Round 5
// 3904.480 us; speedup vs baseline: 1.2003x; 1.0676x over previous
//
#include <hip/hip_runtime.h>

typedef unsigned short u16;
typedef unsigned int   u32;
typedef __attribute__((ext_vector_type(8))) short s8v;   // 8 x bf16 bits (4 VGPRs)
typedef __attribute__((ext_vector_type(4))) float f4v;   // MFMA accumulator

#define B_SZ  64
#define T_LEN 512
#define U_DIM 256
#define E_DIM 300
#define EP    320          // E padded to multiple of 32
#define G3    768          // 3*U
#define NTOT  1536         // both directions concatenated
#define C_DIM 20
#define BT    (B_SZ*T_LEN)

__device__ __forceinline__ float bf2f(u16 h){ return __uint_as_float(((u32)h)<<16); }
__device__ __forceinline__ u16 f2bf(float f){
  u32 u = __float_as_uint(f);
  u32 r = (u + 0x7FFFu + ((u>>16)&1u)) >> 16;   // RNE
  return (u16)r;
}

// ------------- embedding gather f32 -> bf16, K-pad (300 -> 320, zeros) --------
__global__ void embed_pad(const int* __restrict__ x, const float* __restrict__ emb,
                          u16* __restrict__ e){
  int idx = blockIdx.x*256 + threadIdx.x;
  if(idx >= BT*EP) return;
  int row = idx / EP, col = idx - row*EP;
  u16 v = 0;
  if(col < E_DIM) v = f2bf(emb[(size_t)x[row]*E_DIM + col]);
  e[idx] = v;
}

// ------ transpose + concat two f32 [K,768] sources -> bf16 dst[N][Kp] ---------
__global__ void transpose_cc(const float* __restrict__ A, const float* __restrict__ Bm,
                             u16* __restrict__ dst, int K, int Kp, int N){
  int idx = blockIdx.x*256 + threadIdx.x;
  if(idx >= N*Kp) return;
  int n = idx / Kp, k = idx - n*Kp;
  u16 v = 0;
  if(k < K){
    const float* s = (n < G3) ? A : Bm;
    int nn = (n < G3) ? n : n - G3;
    v = f2bf(s[(size_t)k*G3 + nn]);
  }
  dst[idx] = v;
}

// ---------------- GEMM: C[M,1536] = A[M,Kp] @ BT^T + bias (bf16 out) ----------
__global__ __launch_bounds__(256) void gemm_bt(
    const u16* __restrict__ A, const u16* __restrict__ BT_, u16* __restrict__ C,
    int Kp, const float* __restrict__ biasA, const float* __restrict__ biasB)
{
  __shared__ u16 Al[128][40];   // +8 pad breaks bank collisions
  __shared__ u16 Bl[128][40];
  int tid = threadIdx.x;
  int w = tid>>6, l = tid&63, lc = l&15, quad = l>>4;
  int wm = w>>1, wn = w&1;
  int mb = blockIdx.y*128, nb = blockIdx.x*128;

  f4v acc[4][4];
  #pragma unroll
  for(int i=0;i<4;i++)
    #pragma unroll
    for(int j=0;j<4;j++) acc[i][j] = (f4v){0.f,0.f,0.f,0.f};

  int nk = Kp >> 5;
  for(int kt=0; kt<nk; kt++){
    __syncthreads();
    {
      int c0 = tid, c1 = tid + 256;
      int r0 = c0>>2, k80 = c0&3;
      int r1 = c1>>2, k81 = c1&3;
      *(s8v*)&Al[r0][k80*8] = *(const s8v*)(A   + (size_t)(mb+r0)*Kp + kt*32 + k80*8);
      *(s8v*)&Al[r1][k81*8] = *(const s8v*)(A   + (size_t)(mb+r1)*Kp + kt*32 + k81*8);
      *(s8v*)&Bl[r0][k80*8] = *(const s8v*)(BT_ + (size_t)(nb+r0)*Kp + kt*32 + k80*8);
      *(s8v*)&Bl[r1][k81*8] = *(const s8v*)(BT_ + (size_t)(nb+r1)*Kp + kt*32 + k81*8);
    }
    __syncthreads();
    s8v af[4], bf[4];
    #pragma unroll
    for(int i=0;i<4;i++) af[i] = *(const s8v*)&Al[wm*64 + i*16 + lc][quad*8];
    #pragma unroll
    for(int j=0;j<4;j++) bf[j] = *(const s8v*)&Bl[wn*64 + j*16 + lc][quad*8];
    #pragma unroll
    for(int i=0;i<4;i++)
      #pragma unroll
      for(int j=0;j<4;j++)
        acc[i][j] = __builtin_amdgcn_mfma_f32_16x16x32_bf16(af[i], bf[j], acc[i][j],0,0,0);
  }
  #pragma unroll
  for(int j=0;j<4;j++){
    int col = nb + wn*64 + j*16 + lc;
    float bias = (col < G3) ? biasA[col] : biasB[col - G3];
    #pragma unroll
    for(int i=0;i<4;i++){
      int row0 = mb + wm*64 + i*16 + quad*4;
      #pragma unroll
      for(int r=0;r<4;r++)
        C[(size_t)(row0+r)*NTOT + col] = f2bf(acc[i][j][r] + bias);
    }
  }
}

// ---------------- GRU scan, one layer both directions -------------------------
// grid = 8 blocks: dir = blockIdx&1, batch-group = blockIdx>>1 (16 batches each).
// 512 threads = 8 waves; wave w owns u in [32w,32w+32): gate cols {g*256+32w..+32}.
// HYBRID rk residency: ktiles 0-5 (k<192) in VGPRs (36 s8v = 144 regs/wave),
// ktiles 6-7 (k in [192,256)) in LDS (768x64 bf16, staged once).
// Total pressure ~230 < 256 (2 waves/EU budget) so the allocator can keep brk
// resident instead of sinking the loads into the loop (R3/R4 failure mode).
template<int MODE>
__global__ __launch_bounds__(512,2) void gru_scan(
    const u16* __restrict__ xw,    // [BT,1536] bf16 (= X@K + b0, both dirs)
    const u16* __restrict__ rkT,   // [2][768][256] bf16 transposed recurrent kernels
    const float* __restrict__ bF, const float* __restrict__ bB,  // b[2][768] f32
    u16* __restrict__ h1out,       // MODE 0: [BT,512]
    float* __restrict__ h2out)     // MODE 1: [64,512] final states
{
  int dir = blockIdx.x & 1, grp = blockIdx.x >> 1;
  int b0 = grp*16;
  int tid = threadIdx.x;
  int w = tid>>6, l = tid&63, lc = l&15, quad = l>>4;

  __shared__ u16 hb[2][16][264];   // double-buffered h (bf16), +8 pad (2-way banks: free)
  __shared__ u16 rkl[G3][72];      // rk k=[192,256) per col; 64 elems + 8 pad
                                   // row stride 144B=36 banks -> lanes hit 8 banks 2-way: free
  for(int i=tid; i<2*16*264; i+=512) ((u16*)hb)[i] = 0;

  const u16*   rkd  = rkT + (size_t)dir*G3*U_DIM;
  const float* bias = (dir ? bB : bF) + G3;   // row 1 = recurrent bias

  // stage rkl (98 KB data): 768 rows x 64 elems as s8v chunks
  for(int idx=tid; idx<G3*8; idx+=512){
    int row = idx>>3, c8 = idx&7;
    *(s8v*)&rkl[row][c8*8] = *(const s8v*)(rkd + (size_t)row*U_DIM + 192 + c8*8);
  }

  // register-resident B-fragments: brk[gate][sub][ktile 0..5]  (144 VGPRs)
  s8v brk[3][2][6];
  #pragma unroll
  for(int g=0; g<3; g++)
    #pragma unroll
    for(int s=0; s<2; s++){
      int n = g*256 + w*32 + s*16 + lc;
      #pragma unroll
      for(int kt=0; kt<6; kt++)
        brk[g][s][kt] = *(const s8v*)(rkd + (size_t)n*U_DIM + kt*32 + quad*8);
    }
  float bg[3][2];
  #pragma unroll
  for(int g=0;g<3;g++)
    #pragma unroll
    for(int s=0;s<2;s++)
      bg[g][s] = bias[g*256 + w*32 + s*16 + lc];

  int t0 = dir ? (T_LEN-1) : 0;
  long tstride  = dir ? -(long)NTOT      : (long)NTOT;       // xw elems/step
  long hstride  = dir ? -(long)(2*U_DIM) : (long)(2*U_DIM);  // h1out elems/step

  const u16* xwp[4];
  u16* hop[4];
  #pragma unroll
  for(int r=0;r<4;r++){
    int m = quad*4 + r;
    xwp[r] = xw + ((size_t)(b0+m)*T_LEN + t0)*NTOT + dir*G3 + w*32 + lc;
    hop[r] = (MODE==0) ? (h1out + ((size_t)(b0+m)*T_LEN + t0)*(2*U_DIM) + dir*U_DIM + w*32 + lc)
                       : nullptr;
  }

  __syncthreads();

  int cur = 0;
  for(int step=0; step<T_LEN; step++){
    // xw loads for this step (independent of h -> issue before MFMA)
    u16 xu[3][2][4];
    #pragma unroll
    for(int r=0;r<4;r++)
      #pragma unroll
      for(int g=0;g<3;g++)
        #pragma unroll
        for(int s=0;s<2;s++)
          xu[g][s][r] = xwp[r][g*256 + s*16];

    f4v acc[3][2];
    #pragma unroll
    for(int g=0;g<3;g++)
      #pragma unroll
      for(int s=0;s<2;s++) acc[g][s] = (f4v){0.f,0.f,0.f,0.f};

    // ktiles 0..5 from registers
    #pragma unroll
    for(int kt=0; kt<6; kt++){
      s8v a = *(const s8v*)&hb[cur][lc][kt*32 + quad*8];
      #pragma unroll
      for(int g=0;g<3;g++)
        #pragma unroll
        for(int s=0;s<2;s++)
          acc[g][s] = __builtin_amdgcn_mfma_f32_16x16x32_bf16(a, brk[g][s][kt], acc[g][s],0,0,0);
    }
    // ktiles 6..7 from LDS
    #pragma unroll
    for(int kt=6; kt<8; kt++){
      s8v a = *(const s8v*)&hb[cur][lc][kt*32 + quad*8];
      #pragma unroll
      for(int g=0;g<3;g++)
        #pragma unroll
        for(int s=0;s<2;s++){
          int n = g*256 + w*32 + s*16 + lc;
          s8v b = *(const s8v*)&rkl[n][(kt-6)*32 + quad*8];
          acc[g][s] = __builtin_amdgcn_mfma_f32_16x16x32_bf16(a, b, acc[g][s],0,0,0);
        }
    }

    #pragma unroll
    for(int s=0;s<2;s++){
      int u = w*32 + s*16 + lc;
      #pragma unroll
      for(int r=0;r<4;r++){
        int m = quad*4 + r;
        float zf = acc[0][s][r] + bg[0][s] + bf2f(xu[0][s][r]);
        float rf = acc[1][s][r] + bg[1][s] + bf2f(xu[1][s][r]);
        float rh = acc[2][s][r] + bg[2][s];
        float xh = bf2f(xu[2][s][r]);
        zf = 1.f / (1.f + __expf(-zf));
        rf = 1.f / (1.f + __expf(-rf));
        float hc = xh + rf*rh;
        hc = fminf(fmaxf(hc, -15.f), 15.f);
        float e2 = __expf(2.f*hc);
        float th = (e2 - 1.f) / (e2 + 1.f);
        float hp = bf2f(hb[cur][m][u]);
        float hn = zf*hp + (1.f - zf)*th;
        u16 hbf = f2bf(hn);
        hb[cur^1][m][u] = hbf;
        if(MODE == 0)
          hop[r][s*16] = hbf;
        else if(step == T_LEN-1)
          h2out[(size_t)(b0+m)*(2*U_DIM) + dir*U_DIM + u] = hn;
      }
    }

    #pragma unroll
    for(int r=0;r<4;r++){
      xwp[r] += tstride;
      if(MODE==0) hop[r] += hstride;
    }
    __syncthreads();
    cur ^= 1;
  }
}

// ---------------- final projection + softmax (f32 output) ---------------------
__global__ void out_softmax(const float* __restrict__ h2, const float* __restrict__ wout,
                            const float* __restrict__ bout, float* __restrict__ out)
{
  __shared__ float lg[C_DIM];
  int b = blockIdx.x, l = threadIdx.x;   // 64 threads = 1 wave
  float acc[C_DIM];
  #pragma unroll
  for(int c=0;c<C_DIM;c++) acc[c] = 0.f;
  for(int k=l; k<2*U_DIM; k+=64){
    float hv = h2[b*2*U_DIM + k];
    #pragma unroll
    for(int c=0;c<C_DIM;c++) acc[c] += hv * wout[k*C_DIM + c];
  }
  #pragma unroll
  for(int c=0;c<C_DIM;c++){
    float v = acc[c];
    for(int off=32; off; off>>=1) v += __shfl_down(v, off);
    if(l==0) lg[c] = v + bout[c];
  }
  __syncthreads();
  if(l==0){
    float mx = lg[0];
    for(int c=1;c<C_DIM;c++) mx = fmaxf(mx, lg[c]);
    float sum = 0.f, ex[C_DIM];
    for(int c=0;c<C_DIM;c++){ ex[c] = __expf(lg[c]-mx); sum += ex[c]; }
    for(int c=0;c<C_DIM;c++) out[b*C_DIM + c] = ex[c]/sum;
  }
}

extern "C" void kernel_launch(void* const* d_in, const int* in_sizes, int n_in,
                              void* d_out, int out_size, void* d_ws, size_t ws_size,
                              hipStream_t stream)
{
  const int*   x    = (const int*)d_in[0];
  const float* emb  = (const float*)d_in[1];
  const float* k1f  = (const float*)d_in[2];
  const float* rk1f = (const float*)d_in[3];
  const float* b1f  = (const float*)d_in[4];
  const float* k1b  = (const float*)d_in[5];
  const float* rk1b = (const float*)d_in[6];
  const float* b1b  = (const float*)d_in[7];
  const float* k2f  = (const float*)d_in[8];
  const float* rk2f = (const float*)d_in[9];
  const float* b2f  = (const float*)d_in[10];
  const float* k2b  = (const float*)d_in[11];
  const float* rk2b = (const float*)d_in[12];
  const float* b2b  = (const float*)d_in[13];
  const float* wout = (const float*)d_in[14];
  const float* bout = (const float*)d_in[15];

  // workspace layout: small buffers first, then h1/e_pad (aliased), then xwb
  char* ws = (char*)d_ws;
  u16*  k1t   = (u16*)(ws);                       // 983,040 B     [1536,320]
  u16*  k2t   = (u16*)(ws + 983040);              // 1,572,864 B   [1536,512]
  u16*  rkt   = (u16*)(ws + 2555904);             // 1,572,864 B   4x[768,256]
  float* h2   = (float*)(ws + 4128768);           // 131,072 B     [64,512]
  u16*  h1    = (u16*)(ws + 4259840);             // 33,554,432 B  [BT,512]
  u16*  e_pad = (u16*)(ws + 4259840);             // 20,971,520 B  [BT,320] (alias h1)
  u16*  xwb   = (u16*)(ws + 37814272);            // 100,663,296 B [BT,1536]

  transpose_cc<<<(NTOT*EP +255)/256,256,0,stream>>>(k1f, k1b, k1t, E_DIM, EP, NTOT);
  transpose_cc<<<(NTOT*512+255)/256,256,0,stream>>>(k2f, k2b, k2t, 512, 512, NTOT);
  transpose_cc<<<(G3*U_DIM+255)/256,256,0,stream>>>(rk1f, rk1f, rkt,                U_DIM, U_DIM, G3);
  transpose_cc<<<(G3*U_DIM+255)/256,256,0,stream>>>(rk1b, rk1b, rkt + 1*G3*U_DIM,   U_DIM, U_DIM, G3);
  transpose_cc<<<(G3*U_DIM+255)/256,256,0,stream>>>(rk2f, rk2f, rkt + 2*G3*U_DIM,   U_DIM, U_DIM, G3);
  transpose_cc<<<(G3*U_DIM+255)/256,256,0,stream>>>(rk2b, rk2b, rkt + 3*G3*U_DIM,   U_DIM, U_DIM, G3);

  embed_pad<<<(BT*EP)/256,256,0,stream>>>(x, emb, e_pad);

  // layer 1: xw = e @ K1 + b0 ; scan -> h1
  gemm_bt<<<dim3(12,256),256,0,stream>>>(e_pad, k1t, xwb, EP, b1f, b1b);
  gru_scan<0><<<8,512,0,stream>>>(xwb, rkt, b1f, b1b, h1, nullptr);

  // layer 2: xw = h1 @ K2 + b0 ; scan -> h2 (final states only)
  gemm_bt<<<dim3(12,256),256,0,stream>>>(h1, k2t, xwb, 512, b2f, b2b);
  gru_scan<1><<<8,512,0,stream>>>(xwb, rkt + 2*G3*U_DIM, b2f, b2b, nullptr, h2);

  out_softmax<<<64,64,0,stream>>>(h2, wout, bout, (float*)d_out);
}

// Round 6
// 3768.704 us; speedup vs baseline: 1.2436x; 1.0360x over previous
//
#include <hip/hip_runtime.h>

typedef unsigned short u16;
typedef unsigned int   u32;
typedef __attribute__((ext_vector_type(8))) short s8v;   // 8 x bf16 bits (4 VGPRs)
typedef __attribute__((ext_vector_type(4))) float f4v;   // MFMA accumulator

#define B_SZ  64
#define T_LEN 512
#define U_DIM 256
#define E_DIM 300
#define EP    320          // E padded to multiple of 32
#define G3    768          // 3*U
#define NTOT  1536         // both directions concatenated
#define C_DIM 20
#define BT    (B_SZ*T_LEN)

__device__ __forceinline__ float bf2f(u16 h){ return __uint_as_float(((u32)h)<<16); }
__device__ __forceinline__ u16 f2bf(float f){
  u32 u = __float_as_uint(f);
  u32 r = (u + 0x7FFFu + ((u>>16)&1u)) >> 16;   // RNE
  return (u16)r;
}

// ------------- embedding gather f32 -> bf16, K-pad (300 -> 320, zeros) --------
__global__ void embed_pad(const int* __restrict__ x, const float* __restrict__ emb,
                          u16* __restrict__ e){
  int idx = blockIdx.x*256 + threadIdx.x;
  if(idx >= BT*EP) return;
  int row = idx / EP, col = idx - row*EP;
  u16 v = 0;
  if(col < E_DIM) v = f2bf(emb[(size_t)x[row]*E_DIM + col]);
  e[idx] = v;
}

// ------ transpose + concat two f32 [K,768] sources -> bf16 dst[N][Kp] ---------
__global__ void transpose_cc(const float* __restrict__ A, const float* __restrict__ Bm,
                             u16* __restrict__ dst, int K, int Kp, int N){
  int idx = blockIdx.x*256 + threadIdx.x;
  if(idx >= N*Kp) return;
  int n = idx / Kp, k = idx - n*Kp;
  u16 v = 0;
  if(k < K){
    const float* s = (n < G3) ? A : Bm;
    int nn = (n < G3) ? n : n - G3;
    v = f2bf(s[(size_t)k*G3 + nn]);
  }
  dst[idx] = v;
}

// ---------------- GEMM: C[M,1536] = A[M,Kp] @ BT^T + bias (bf16 out) ----------
__global__ __launch_bounds__(256) void gemm_bt(
    const u16* __restrict__ A, const u16* __restrict__ BT_, u16* __restrict__ C,
    int Kp, const float* __restrict__ biasA, const float* __restrict__ biasB)
{
  __shared__ u16 Al[128][40];   // +8 pad breaks bank collisions
  __shared__ u16 Bl[128][40];
  int tid = threadIdx.x;
  int w = tid>>6, l = tid&63, lc = l&15, quad = l>>4;
  int wm = w>>1, wn = w&1;
  int mb = blockIdx.y*128, nb = blockIdx.x*128;

  f4v acc[4][4];
  #pragma unroll
  for(int i=0;i<4;i++)
    #pragma unroll
    for(int j=0;j<4;j++) acc[i][j] = (f4v){0.f,0.f,0.f,0.f};

  int nk = Kp >> 5;
  for(int kt=0; kt<nk; kt++){
    __syncthreads();
    {
      int c0 = tid, c1 = tid + 256;
      int r0 = c0>>2, k80 = c0&3;
      int r1 = c1>>2, k81 = c1&3;
      *(s8v*)&Al[r0][k80*8] = *(const s8v*)(A   + (size_t)(mb+r0)*Kp + kt*32 + k80*8);
      *(s8v*)&Al[r1][k81*8] = *(const s8v*)(A   + (size_t)(mb+r1)*Kp + kt*32 + k81*8);
      *(s8v*)&Bl[r0][k80*8] = *(const s8v*)(BT_ + (size_t)(nb+r0)*Kp + kt*32 + k80*8);
      *(s8v*)&Bl[r1][k81*8] = *(const s8v*)(BT_ + (size_t)(nb+r1)*Kp + kt*32 + k81*8);
    }
    __syncthreads();
    s8v af[4], bf[4];
    #pragma unroll
    for(int i=0;i<4;i++) af[i] = *(const s8v*)&Al[wm*64 + i*16 + lc][quad*8];
    #pragma unroll
    for(int j=0;j<4;j++) bf[j] = *(const s8v*)&Bl[wn*64 + j*16 + lc][quad*8];
    #pragma unroll
    for(int i=0;i<4;i++)
      #pragma unroll
      for(int j=0;j<4;j++)
        acc[i][j] = __builtin_amdgcn_mfma_f32_16x16x32_bf16(af[i], bf[j], acc[i][j],0,0,0);
  }
  #pragma unroll
  for(int j=0;j<4;j++){
    int col = nb + wn*64 + j*16 + lc;
    float bias = (col < G3) ? biasA[col] : biasB[col - G3];
    #pragma unroll
    for(int i=0;i<4;i++){
      int row0 = mb + wm*64 + i*16 + quad*4;
      #pragma unroll
      for(int r=0;r<4;r++)
        C[(size_t)(row0+r)*NTOT + col] = f2bf(acc[i][j][r] + bias);
    }
  }
}

// ---------------- GRU scan, one layer both directions -------------------------
// grid = 8 blocks: dir = blockIdx&1, batch-group = blockIdx>>1 (16 batches each).
// 512 threads = 8 waves; wave w owns u in [32w,32w+32): gate cols {g*256+32w..+32}.
// HYBRID rk residency: ktiles 0-5 in VGPRs (144 regs/wave, PINNED via asm so the
// allocator cannot sink/remat the loads back into the loop — R4/R5 failure mode),
// ktiles 6-7 in LDS (768x64 bf16, staged once).
template<int MODE>
__global__ __launch_bounds__(512,2) void gru_scan(
    const u16* __restrict__ xw,    // [BT,1536] bf16 (= X@K + b0, both dirs)
    const u16* __restrict__ rkT,   // [2][768][256] bf16 transposed recurrent kernels
    const float* __restrict__ bF, const float* __restrict__ bB,  // b[2][768] f32
    u16* __restrict__ h1out,       // MODE 0: [BT,512]
    float* __restrict__ h2out)     // MODE 1: [64,512] final states
{
  int dir = blockIdx.x & 1, grp = blockIdx.x >> 1;
  int b0 = grp*16;
  int tid = threadIdx.x;
  int w = tid>>6, l = tid&63, lc = l&15, quad = l>>4;

  __shared__ u16 hb[2][16][264];   // double-buffered h (bf16), +8 pad (2-way banks: free)
  __shared__ u16 rkl[G3][72];      // rk k=[192,256) per col; 64 elems + 8 pad
  for(int i=tid; i<2*16*264; i+=512) ((u16*)hb)[i] = 0;

  const u16*   rkd  = rkT + (size_t)dir*G3*U_DIM;
  const float* bias = (dir ? bB : bF) + G3;   // row 1 = recurrent bias

  // stage rkl: 768 rows x 64 elems as s8v chunks
  for(int idx=tid; idx<G3*8; idx+=512){
    int row = idx>>3, c8 = idx&7;
    *(s8v*)&rkl[row][c8*8] = *(const s8v*)(rkd + (size_t)row*U_DIM + 192 + c8*8);
  }

  // register-resident B-fragments: brk[gate][sub][ktile 0..5]  (144 VGPRs)
  s8v brk[3][2][6];
  #pragma unroll
  for(int g=0; g<3; g++)
    #pragma unroll
    for(int s=0; s<2; s++){
      int n = g*256 + w*32 + s*16 + lc;
      #pragma unroll
      for(int kt=0; kt<6; kt++)
        brk[g][s][kt] = *(const s8v*)(rkd + (size_t)n*U_DIM + kt*32 + quad*8);
    }
  // PIN: opaque volatile asm redefines each fragment -> loads execute exactly
  // once; values must stay live in VGPRs across the whole scan loop.
  #pragma unroll
  for(int g=0; g<3; g++)
    #pragma unroll
    for(int s=0; s<2; s++)
      #pragma unroll
      for(int kt=0; kt<6; kt++)
        asm volatile("" : "+v"(brk[g][s][kt]));

  float bg[3][2];
  #pragma unroll
  for(int g=0;g<3;g++)
    #pragma unroll
    for(int s=0;s<2;s++)
      bg[g][s] = bias[g*256 + w*32 + s*16 + lc];

  int t0 = dir ? (T_LEN-1) : 0;
  long tstride  = dir ? -(long)NTOT      : (long)NTOT;       // xw elems/step
  long hstride  = dir ? -(long)(2*U_DIM) : (long)(2*U_DIM);  // h1out elems/step

  const u16* xwp[4];
  u16* hop[4];
  #pragma unroll
  for(int r=0;r<4;r++){
    int m = quad*4 + r;
    xwp[r] = xw + ((size_t)(b0+m)*T_LEN + t0)*NTOT + dir*G3 + w*32 + lc;
    hop[r] = (MODE==0) ? (h1out + ((size_t)(b0+m)*T_LEN + t0)*(2*U_DIM) + dir*U_DIM + w*32 + lc)
                       : nullptr;
  }

  __syncthreads();

  int cur = 0;
  for(int step=0; step<T_LEN; step++){
    // xw loads for this step (independent of h -> issue before MFMA)
    u16 xu[3][2][4];
    #pragma unroll
    for(int r=0;r<4;r++)
      #pragma unroll
      for(int g=0;g<3;g++)
        #pragma unroll
        for(int s=0;s<2;s++)
          xu[g][s][r] = xwp[r][g*256 + s*16];

    f4v acc[3][2];
    #pragma unroll
    for(int g=0;g<3;g++)
      #pragma unroll
      for(int s=0;s<2;s++) acc[g][s] = (f4v){0.f,0.f,0.f,0.f};

    // ktiles 0..5 from registers
    #pragma unroll
    for(int kt=0; kt<6; kt++){
      s8v a = *(const s8v*)&hb[cur][lc][kt*32 + quad*8];
      #pragma unroll
      for(int g=0;g<3;g++)
        #pragma unroll
        for(int s=0;s<2;s++)
          acc[g][s] = __builtin_amdgcn_mfma_f32_16x16x32_bf16(a, brk[g][s][kt], acc[g][s],0,0,0);
    }
    // ktiles 6..7 from LDS
    #pragma unroll
    for(int kt=6; kt<8; kt++){
      s8v a = *(const s8v*)&hb[cur][lc][kt*32 + quad*8];
      #pragma unroll
      for(int g=0;g<3;g++)
        #pragma unroll
        for(int s=0;s<2;s++){
          int n = g*256 + w*32 + s*16 + lc;
          s8v b = *(const s8v*)&rkl[n][(kt-6)*32 + quad*8];
          acc[g][s] = __builtin_amdgcn_mfma_f32_16x16x32_bf16(a, b, acc[g][s],0,0,0);
        }
    }

    #pragma unroll
    for(int s=0;s<2;s++){
      int u = w*32 + s*16 + lc;
      #pragma unroll
      for(int r=0;r<4;r++){
        int m = quad*4 + r;
        float zf = acc[0][s][r] + bg[0][s] + bf2f(xu[0][s][r]);
        float rf = acc[1][s][r] + bg[1][s] + bf2f(xu[1][s][r]);
        float rh = acc[2][s][r] + bg[2][s];
        float xh = bf2f(xu[2][s][r]);
        zf = 1.f / (1.f + __expf(-zf));
        rf = 1.f / (1.f + __expf(-rf));
        float hc = xh + rf*rh;
        hc = fminf(fmaxf(hc, -15.f), 15.f);
        float e2 = __expf(2.f*hc);
        float th = (e2 - 1.f) / (e2 + 1.f);
        float hp = bf2f(hb[cur][m][u]);
        float hn = zf*hp + (1.f - zf)*th;
        u16 hbf = f2bf(hn);
        hb[cur^1][m][u] = hbf;
        if(MODE == 0)
          hop[r][s*16] = hbf;
        else if(step == T_LEN-1)
          h2out[(size_t)(b0+m)*(2*U_DIM) + dir*U_DIM + u] = hn;
      }
    }

    #pragma unroll
    for(int r=0;r<4;r++){
      xwp[r] += tstride;
      if(MODE==0) hop[r] += hstride;
    }
    __syncthreads();
    cur ^= 1;
  }
}

// ---------------- final projection + softmax (f32 output) ---------------------
__global__ void out_softmax(const float* __restrict__ h2, const float* __restrict__ wout,
                            const float* __restrict__ bout, float* __restrict__ out)
{
  __shared__ float lg[C_DIM];
  int b = blockIdx.x, l = threadIdx.x;   // 64 threads = 1 wave
  float acc[C_DIM];
  #pragma unroll
  for(int c=0;c<C_DIM;c++) acc[c] = 0.f;
  for(int k=l; k<2*U_DIM; k+=64){
    float hv = h2[b*2*U_DIM + k];
    #pragma unroll
    for(int c=0;c<C_DIM;c++) acc[c] += hv * wout[k*C_DIM + c];
  }
  #pragma unroll
  for(int c=0;c<C_DIM;c++){
    float v = acc[c];
    for(int off=32; off; off>>=1) v += __shfl_down(v, off);
    if(l==0) lg[c] = v + bout[c];
  }
  __syncthreads();
  if(l==0){
    float mx = lg[0];
    for(int c=1;c<C_DIM;c++) mx = fmaxf(mx, lg[c]);
    float sum = 0.f, ex[C_DIM];
    for(int c=0;c<C_DIM;c++){ ex[c] = __expf(lg[c]-mx); sum += ex[c]; }
    for(int c=0;c<C_DIM;c++) out[b*C_DIM + c] = ex[c]/sum;
  }
}

extern "C" void kernel_launch(void* const* d_in, const int* in_sizes, int n_in,
                              void* d_out, int out_size, void* d_ws, size_t ws_size,
                              hipStream_t stream)
{
  const int*   x    = (const int*)d_in[0];
  const float* emb  = (const float*)d_in[1];
  const float* k1f  = (const float*)d_in[2];
  const float* rk1f = (const float*)d_in[3];
  const float* b1f  = (const float*)d_in[4];
  const float* k1b  = (const float*)d_in[5];
  const float* rk1b = (const float*)d_in[6];
  const float* b1b  = (const float*)d_in[7];
  const float* k2f  = (const float*)d_in[8];
  const float* rk2f = (const float*)d_in[9];
  const float* b2f  = (const float*)d_in[10];
  const float* k2b  = (const float*)d_in[11];
  const float* rk2b = (const float*)d_in[12];
  const float* b2b  = (const float*)d_in[13];
  const float* wout = (const float*)d_in[14];
  const float* bout = (const float*)d_in[15];

  // workspace layout: small buffers first, then h1/e_pad (aliased), then xwb
  char* ws = (char*)d_ws;
  u16*  k1t   = (u16*)(ws);                       // 983,040 B     [1536,320]
  u16*  k2t   = (u16*)(ws + 983040);              // 1,572,864 B   [1536,512]
  u16*  rkt   = (u16*)(ws + 2555904);             // 1,572,864 B   4x[768,256]
  float* h2   = (float*)(ws + 4128768);           // 131,072 B     [64,512]
  u16*  h1    = (u16*)(ws + 4259840);             // 33,554,432 B  [BT,512]
  u16*  e_pad = (u16*)(ws + 4259840);             // 20,971,520 B  [BT,320] (alias h1)
  u16*  xwb   = (u16*)(ws + 37814272);            // 100,663,296 B [BT,1536]

  transpose_cc<<<(NTOT*EP +255)/256,256,0,stream>>>(k1f, k1b, k1t, E_DIM, EP, NTOT);
  transpose_cc<<<(NTOT*512+255)/256,256,0,stream>>>(k2f, k2b, k2t, 512, 512, NTOT);
  transpose_cc<<<(G3*U_DIM+255)/256,256,0,stream>>>(rk1f, rk1f, rkt,                U_DIM, U_DIM, G3);
  transpose_cc<<<(G3*U_DIM+255)/256,256,0,stream>>>(rk1b, rk1b, rkt + 1*G3*U_DIM,   U_DIM, U_DIM, G3);
  transpose_cc<<<(G3*U_DIM+255)/256,256,0,stream>>>(rk2f, rk2f, rkt + 2*G3*U_DIM,   U_DIM, U_DIM, G3);
  transpose_cc<<<(G3*U_DIM+255)/256,256,0,stream>>>(rk2b, rk2b, rkt + 3*G3*U_DIM,   U_DIM, U_DIM, G3);

  embed_pad<<<(BT*EP)/256,256,0,stream>>>(x, emb, e_pad);

  // layer 1: xw = e @ K1 + b0 ; scan -> h1
  gemm_bt<<<dim3(12,256),256,0,stream>>>(e_pad, k1t, xwb, EP, b1f, b1b);
  gru_scan<0><<<8,512,0,stream>>>(xwb, rkt, b1f, b1b, h1, nullptr);

  // layer 2: xw = h1 @ K2 + b0 ; scan -> h2 (final states only)
  gemm_bt<<<dim3(12,256),256,0,stream>>>(h1, k2t, xwb, 512, b2f, b2b);
  gru_scan<1><<<8,512,0,stream>>>(xwb, rkt + 2*G3*U_DIM, b2f, b2b, nullptr, h2);

  out_softmax<<<64,64,0,stream>>>(h2, wout, bout, (float*)d_out);
}